// Round 3
// baseline (220.075 us; speedup 1.0000x reference)
//
#include <hip/hip_runtime.h>

typedef _Float16 f16;
typedef _Float16 f16x8 __attribute__((ext_vector_type(8)));
typedef _Float16 f16x4 __attribute__((ext_vector_type(4)));
typedef float    f32x4 __attribute__((ext_vector_type(4)));

// Problem: B=2, S=2048, E=2048, H=16, HKV=4, D=128, WINDOW=256
// Reference quirk: q is ALSO indexed by idx=repeat(arange(4),4) -> only q heads
// 0..3 (Wq rows 0..511) used; output head i = attn_{i//4}, so Wo pre-folds:
// Wr[e,g*128+d] = sum_j Wo[e,(4g+j)*128+d].
// I/O: inputs f32, output f32. Internals: f16 storage + f16 MFMA, f32 accum.
//
// R8 (= R7 retry + WAR hardening): GEMMs restructured for latency-hiding
// (R6 post-mortem: latency-bound at 1.5 blocks/CU, vmcnt(0)-drain per K-step):
//  - tile 64x128 (4 waves, each 32x64) -> qkv 768 blocks, out 1024 blocks
//  - 3 LDS buffers, depth-2 prefetch, raw s_barrier + counted vmcnt(3)
//  - per-iter wait is "vmcnt(3) lgkmcnt(0)": lgkmcnt(0) pins this wave's
//    prior ds_reads before the barrier (rule #18: MFMA can sink past
//    s_barrier, so MFMA-use alone doesn't guarantee ds_read retirement).

__device__ __forceinline__ void load_lds16(const void* g, void* l) {
    __builtin_amdgcn_global_load_lds(
        (__attribute__((address_space(1))) void*)(g),
        (__attribute__((address_space(3))) void*)(l), 16, 0, 0);
}

// ---------------------------------------------------------------------------
// Pre-pass: f32->f16 convert (X, Wq rows 0..511, Wk, Wv) + Wo GQA fold.
// ---------------------------------------------------------------------------
__global__ __launch_bounds__(256)
void cvt_fold(const float* __restrict__ X, const float* __restrict__ Wq,
              const float* __restrict__ Wk, const float* __restrict__ Wv,
              const float* __restrict__ Wo,
              f16* __restrict__ Xh, f16* __restrict__ Wqh,
              f16* __restrict__ Wkh, f16* __restrict__ Wvh, f16* __restrict__ Wr)
{
    int blk = blockIdx.x;
    if (blk < 11264) {
        size_t o = ((size_t)blk * 256 + threadIdx.x) * 4;
        const float* src; f16* dst; size_t off;
        if (o < 8388608)       { src = X;  dst = Xh;  off = o; }
        else if (o < 9437184)  { src = Wq; dst = Wqh; off = o - 8388608; }
        else if (o < 10485760) { src = Wk; dst = Wkh; off = o - 9437184; }
        else                   { src = Wv; dst = Wvh; off = o - 10485760; }
        float4 v = *(const float4*)(src + off);
        f16x4 b;
        b[0] = (f16)v.x; b[1] = (f16)v.y; b[2] = (f16)v.z; b[3] = (f16)v.w;
        *(f16x4*)(dst + off) = b;
    } else {
        size_t t = (size_t)(blk - 11264) * 256 + threadIdx.x;  // < 262144
        size_t o = t * 4;
        int e = (int)(o >> 9);
        int c = (int)(o & 511);
        int g = c >> 7, d0 = c & 127;
        const float* src = Wo + (size_t)e * 2048 + g * 512 + d0;
        float4 a0 = *(const float4*)(src);
        float4 a1 = *(const float4*)(src + 128);
        float4 a2 = *(const float4*)(src + 256);
        float4 a3 = *(const float4*)(src + 384);
        f16x4 ob;
        ob[0] = (f16)(a0.x + a1.x + a2.x + a3.x);
        ob[1] = (f16)(a0.y + a1.y + a2.y + a3.y);
        ob[2] = (f16)(a0.z + a1.z + a2.z + a3.z);
        ob[3] = (f16)(a0.w + a1.w + a2.w + a3.w);
        *(f16x4*)(Wr + o) = ob;
    }
}

// Shared staging geometry for the 64x128 tile, BK=32:
//   combined LDS tile = A[64][32] then B[128][32] = 192 rows * 32 f16 = 6144.
//   768 16B-chunks = 12 wave-loads; wave w owns slots 3w..3w+2.
#define STAGE3(t, buf)                                          \
    {                                                           \
        load_lds16(gsrc0 + (t) * 32, &S[buf][loff0]);           \
        load_lds16(gsrc1 + (t) * 32, &S[buf][loff1]);           \
        load_lds16(gsrc2 + (t) * 32, &S[buf][loff2]);           \
    }

// ---------------------------------------------------------------------------
// Fused QKV projection GEMM. C[m,n] = sum_k X[m,k]*W[n,k]; M=4096,N=512,K=2048.
// z: (Wq' | Wk | Wv). z<2: write (B,4,S,D); z==2: (B,4,D,S) transposed.
// ---------------------------------------------------------------------------
__global__ __launch_bounds__(256)
void qkv_gemm(const f16* __restrict__ X, const f16* __restrict__ Wq,
              const f16* __restrict__ Wk, const f16* __restrict__ Wv,
              f16* __restrict__ Qo, f16* __restrict__ Ko, f16* __restrict__ Vo)
{
    const int z = blockIdx.z;
    const f16* Bw = (z == 0) ? Wq : (z == 1) ? Wk : Wv;
    f16* C = (z == 0) ? Qo : (z == 1) ? Ko : Vo;
    const int K = 2048;
    const int NSTEP = 64;

    __shared__ __align__(16) f16 S[3][6144];

    const int tid = threadIdx.x;
    const int wave = tid >> 6, lane = tid & 63;
    const int lrow = lane & 15, lquad = lane >> 4;
    const int wr = wave >> 1, wc = wave & 1;
    const int m0 = blockIdx.y * 64, n0 = blockIdx.x * 128;

    // staging slots for this wave (source-side chunk swizzle, mirrored on read)
    const f16* gsrc0; const f16* gsrc1; const f16* gsrc2;
    int loff0, loff1, loff2;
    {
        int s;
        s = (wave * 3 + 0) * 64 + lane;
        { int isB = s >= 256; int s2 = isB ? s - 256 : s; int row = s2 >> 2, kc = s2 & 3;
          int kcs = kc ^ ((row >> 1) & 3); loff0 = s * 8;
          gsrc0 = (isB ? Bw + (size_t)(n0 + row) * K : X + (size_t)(m0 + row) * K) + kcs * 8; }
        s = (wave * 3 + 1) * 64 + lane;
        { int isB = s >= 256; int s2 = isB ? s - 256 : s; int row = s2 >> 2, kc = s2 & 3;
          int kcs = kc ^ ((row >> 1) & 3); loff1 = s * 8;
          gsrc1 = (isB ? Bw + (size_t)(n0 + row) * K : X + (size_t)(m0 + row) * K) + kcs * 8; }
        s = (wave * 3 + 2) * 64 + lane;
        { int isB = s >= 256; int s2 = isB ? s - 256 : s; int row = s2 >> 2, kc = s2 & 3;
          int kcs = kc ^ ((row >> 1) & 3); loff2 = s * 8;
          gsrc2 = (isB ? Bw + (size_t)(n0 + row) * K : X + (size_t)(m0 + row) * K) + kcs * 8; }
    }

    // swizzled read offsets (f16 units); B region starts at 2048
    int aoff[2], boff[4];
#pragma unroll
    for (int t = 0; t < 2; t++) {
        int ra = wr * 32 + t * 16 + lrow;
        aoff[t] = ra * 32 + ((lquad ^ ((ra >> 1) & 3)) << 3);
    }
#pragma unroll
    for (int t = 0; t < 4; t++) {
        int rb = wc * 64 + t * 16 + lrow;
        boff[t] = 2048 + rb * 32 + ((lquad ^ ((rb >> 1) & 3)) << 3);
    }

    f32x4 acc[2][4];
    const f32x4 z4 = {0.f, 0.f, 0.f, 0.f};
#pragma unroll
    for (int i = 0; i < 2; i++) for (int j = 0; j < 4; j++) acc[i][j] = z4;

    STAGE3(0, 0);
    STAGE3(1, 1);

    int buf = 0;
    for (int t = 0; t < NSTEP; ++t) {
        if (t < NSTEP - 2) {
            asm volatile("s_waitcnt vmcnt(3) lgkmcnt(0)" ::: "memory");
            __builtin_amdgcn_s_barrier();
            int nb = buf + 2; if (nb >= 3) nb -= 3;
            STAGE3(t + 2, nb);
        } else if (t == NSTEP - 2) {
            asm volatile("s_waitcnt vmcnt(3) lgkmcnt(0)" ::: "memory");
            __builtin_amdgcn_s_barrier();
        } else {
            asm volatile("s_waitcnt vmcnt(0) lgkmcnt(0)" ::: "memory");
            __builtin_amdgcn_s_barrier();
        }
        f16x8 af[2], bf[4];
#pragma unroll
        for (int mt = 0; mt < 2; mt++) af[mt] = *(const f16x8*)(&S[buf][aoff[mt]]);
#pragma unroll
        for (int nt = 0; nt < 4; nt++) bf[nt] = *(const f16x8*)(&S[buf][boff[nt]]);
#pragma unroll
        for (int mt = 0; mt < 2; mt++)
#pragma unroll
            for (int nt = 0; nt < 4; nt++)
                acc[mt][nt] = __builtin_amdgcn_mfma_f32_16x16x32_f16(af[mt], bf[nt], acc[mt][nt], 0, 0, 0);
        buf += 1; if (buf == 3) buf = 0;
    }

    if (z < 2) {
#pragma unroll
        for (int mt = 0; mt < 2; mt++) {
            int mbase = m0 + wr * 32 + mt * 16 + lquad * 4;
#pragma unroll
            for (int r = 0; r < 4; r++) {
                int m = mbase + r;
                int b = m >> 11, s = m & 2047;
#pragma unroll
                for (int nt = 0; nt < 4; nt++) {
                    int n = n0 + wc * 64 + nt * 16 + lrow;
                    int h = n >> 7, d = n & 127;
                    C[(size_t)(((b * 4 + h) << 11) + s) * 128 + d] = (f16)acc[mt][nt][r];
                }
            }
        }
    } else {
#pragma unroll
        for (int mt = 0; mt < 2; mt++) {
            int mbase = m0 + wr * 32 + mt * 16 + lquad * 4;
            int b = mbase >> 11, s = mbase & 2047;
#pragma unroll
            for (int nt = 0; nt < 4; nt++) {
                int n = n0 + wc * 64 + nt * 16 + lrow;
                int h = n >> 7, d = n & 127;
                f16x4 pk;
#pragma unroll
                for (int r = 0; r < 4; r++) pk[r] = (f16)acc[mt][nt][r];
                *(f16x4*)(C + ((size_t)((b * 4 + h) * 128 + d) << 11) + s) = pk;
            }
        }
    }
}

// ---------------------------------------------------------------------------
// Sliding-window attention, one wave per 16 query rows (unchanged).
// Q,K: (B,4,S,D); V: (B,4,D,S) transposed; AO: (B,S,512)
// ---------------------------------------------------------------------------
__global__ __launch_bounds__(64)
void attn_win(const f16* __restrict__ Q, const f16* __restrict__ Kc,
              const f16* __restrict__ Vt, f16* __restrict__ AO)
{
    const int bg = blockIdx.y;
    const int b = bg >> 2, g = bg & 3;
    const int qbase = blockIdx.x * 16;
    const int lane = threadIdx.x;
    const int lrow = lane & 15, lquad = lane >> 4;

    const f16* Qb = Q  + (size_t)(b * 4 + g) * (2048 * 128);
    const f16* Kb = Kc + (size_t)(b * 4 + g) * (2048 * 128);
    const f16* Vb = Vt + (size_t)(b * 4 + g) * (128 * 2048);

    __shared__ __align__(16) f16 Pl[16 * 128];

    f16x8 qf[4];
    for (int ks = 0; ks < 4; ks++)
        qf[ks] = *(const f16x8*)(Qb + (size_t)(qbase + lrow) * 128 + ks * 32 + lquad * 8);

    float m_i[4], l_i[4];
    f32x4 oa[8];
    const f32x4 z4 = {0.f, 0.f, 0.f, 0.f};
    for (int r = 0; r < 4; r++) { m_i[r] = -30000.f; l_i[r] = 0.f; }
    for (int nt = 0; nt < 8; nt++) oa[nt] = z4;

    const int t0 = (qbase >= 256) ? (((qbase - 255) >> 7) << 7) : 0;
    for (int kt = t0; kt <= qbase + 15; kt += 128) {
        f32x4 sc[8];
        for (int nt = 0; nt < 8; nt++) sc[nt] = z4;
        for (int nt = 0; nt < 8; nt++) {
            for (int ks = 0; ks < 4; ks++) {
                f16x8 kf = *(const f16x8*)(Kb + (size_t)(kt + nt * 16 + lrow) * 128 + ks * 32 + lquad * 8);
                sc[nt] = __builtin_amdgcn_mfma_f32_16x16x32_f16(qf[ks], kf, sc[nt], 0, 0, 0);
            }
        }
        for (int r = 0; r < 4; r++) {
            const int qi = qbase + lquad * 4 + r;
            float rmax = -60000.f;
            for (int nt = 0; nt < 8; nt++) {
                int kj = kt + nt * 16 + lrow;
                float sval = sc[nt][r];
                bool ok = (kj <= qi) && (kj + 256 > qi);
                sval = ok ? sval : -60000.f;
                sc[nt][r] = sval;
                rmax = fmaxf(rmax, sval);
            }
            rmax = fmaxf(rmax, __shfl_xor(rmax, 1));
            rmax = fmaxf(rmax, __shfl_xor(rmax, 2));
            rmax = fmaxf(rmax, __shfl_xor(rmax, 4));
            rmax = fmaxf(rmax, __shfl_xor(rmax, 8));
            float mold = m_i[r];
            float mnew = fmaxf(mold, rmax);
            float alpha = __expf(mold - mnew);
            m_i[r] = mnew;
            float rsum = 0.f;
            for (int nt = 0; nt < 8; nt++) {
                float p = __expf(sc[nt][r] - mnew);
                sc[nt][r] = p;
                rsum += p;
            }
            rsum += __shfl_xor(rsum, 1);
            rsum += __shfl_xor(rsum, 2);
            rsum += __shfl_xor(rsum, 4);
            rsum += __shfl_xor(rsum, 8);
            l_i[r] = l_i[r] * alpha + rsum;
            for (int nt = 0; nt < 8; nt++) oa[nt][r] *= alpha;
        }
        for (int nt = 0; nt < 8; nt++)
            for (int r = 0; r < 4; r++)
                Pl[(lquad * 4 + r) * 128 + nt * 16 + lrow] = (f16)sc[nt][r];
        __syncthreads();
        f16x8 pf[4];
        for (int ks = 0; ks < 4; ks++)
            pf[ks] = *(const f16x8*)(Pl + lrow * 128 + ks * 32 + lquad * 8);
        for (int nt = 0; nt < 8; nt++) {
            for (int ks = 0; ks < 4; ks++) {
                f16x8 vf = *(const f16x8*)(Vb + (size_t)(nt * 16 + lrow) * 2048 + kt + ks * 32 + lquad * 8);
                oa[nt] = __builtin_amdgcn_mfma_f32_16x16x32_f16(pf[ks], vf, oa[nt], 0, 0, 0);
            }
        }
        __syncthreads();
    }
    float inv[4];
    for (int r = 0; r < 4; r++) inv[r] = (l_i[r] > 0.f) ? 1.f / l_i[r] : 0.f;
    for (int nt = 0; nt < 8; nt++) {
        for (int r = 0; r < 4; r++) {
            int q = qbase + lquad * 4 + r;
            int d = nt * 16 + lrow;
            AO[(size_t)(b * 2048 + q) * 512 + g * 128 + d] = (f16)(oa[nt][r] * inv[r]);
        }
    }
}

// ---------------------------------------------------------------------------
// Output GEMM: out = AO @ Wr^T + bo, f32 out. M=4096, N=2048, K=512.
// Same 64x128 tile + 3-buffer counted-vmcnt pipeline as qkv_gemm.
// ---------------------------------------------------------------------------
__global__ __launch_bounds__(256)
void out_gemm(const f16* __restrict__ A, const f16* __restrict__ Bw,
              const float* __restrict__ bias, float* __restrict__ C)
{
    const int K = 512, N = 2048;
    const int NSTEP = 16;

    __shared__ __align__(16) f16 S[3][6144];

    const int tid = threadIdx.x;
    const int wave = tid >> 6, lane = tid & 63;
    const int lrow = lane & 15, lquad = lane >> 4;
    const int wr = wave >> 1, wc = wave & 1;
    const int m0 = blockIdx.y * 64, n0 = blockIdx.x * 128;

    const f16* gsrc0; const f16* gsrc1; const f16* gsrc2;
    int loff0, loff1, loff2;
    {
        int s;
        s = (wave * 3 + 0) * 64 + lane;
        { int isB = s >= 256; int s2 = isB ? s - 256 : s; int row = s2 >> 2, kc = s2 & 3;
          int kcs = kc ^ ((row >> 1) & 3); loff0 = s * 8;
          gsrc0 = (isB ? Bw + (size_t)(n0 + row) * K : A + (size_t)(m0 + row) * K) + kcs * 8; }
        s = (wave * 3 + 1) * 64 + lane;
        { int isB = s >= 256; int s2 = isB ? s - 256 : s; int row = s2 >> 2, kc = s2 & 3;
          int kcs = kc ^ ((row >> 1) & 3); loff1 = s * 8;
          gsrc1 = (isB ? Bw + (size_t)(n0 + row) * K : A + (size_t)(m0 + row) * K) + kcs * 8; }
        s = (wave * 3 + 2) * 64 + lane;
        { int isB = s >= 256; int s2 = isB ? s - 256 : s; int row = s2 >> 2, kc = s2 & 3;
          int kcs = kc ^ ((row >> 1) & 3); loff2 = s * 8;
          gsrc2 = (isB ? Bw + (size_t)(n0 + row) * K : A + (size_t)(m0 + row) * K) + kcs * 8; }
    }

    int aoff[2], boff[4];
#pragma unroll
    for (int t = 0; t < 2; t++) {
        int ra = wr * 32 + t * 16 + lrow;
        aoff[t] = ra * 32 + ((lquad ^ ((ra >> 1) & 3)) << 3);
    }
#pragma unroll
    for (int t = 0; t < 4; t++) {
        int rb = wc * 64 + t * 16 + lrow;
        boff[t] = 2048 + rb * 32 + ((lquad ^ ((rb >> 1) & 3)) << 3);
    }

    f32x4 acc[2][4];
    const f32x4 z4 = {0.f, 0.f, 0.f, 0.f};
#pragma unroll
    for (int i = 0; i < 2; i++) for (int j = 0; j < 4; j++) acc[i][j] = z4;

    STAGE3(0, 0);
    STAGE3(1, 1);

    int buf = 0;
    for (int t = 0; t < NSTEP; ++t) {
        if (t < NSTEP - 2) {
            asm volatile("s_waitcnt vmcnt(3) lgkmcnt(0)" ::: "memory");
            __builtin_amdgcn_s_barrier();
            int nb = buf + 2; if (nb >= 3) nb -= 3;
            STAGE3(t + 2, nb);
        } else if (t == NSTEP - 2) {
            asm volatile("s_waitcnt vmcnt(3) lgkmcnt(0)" ::: "memory");
            __builtin_amdgcn_s_barrier();
        } else {
            asm volatile("s_waitcnt vmcnt(0) lgkmcnt(0)" ::: "memory");
            __builtin_amdgcn_s_barrier();
        }
        f16x8 af[2], bf[4];
#pragma unroll
        for (int mt = 0; mt < 2; mt++) af[mt] = *(const f16x8*)(&S[buf][aoff[mt]]);
#pragma unroll
        for (int nt = 0; nt < 4; nt++) bf[nt] = *(const f16x8*)(&S[buf][boff[nt]]);
#pragma unroll
        for (int mt = 0; mt < 2; mt++)
#pragma unroll
            for (int nt = 0; nt < 4; nt++)
                acc[mt][nt] = __builtin_amdgcn_mfma_f32_16x16x32_f16(af[mt], bf[nt], acc[mt][nt], 0, 0, 0);
        buf += 1; if (buf == 3) buf = 0;
    }

#pragma unroll
    for (int nt = 0; nt < 4; nt++) {
        int n = n0 + wc * 64 + nt * 16 + lrow;
        float bv2 = bias[n];
#pragma unroll
        for (int mt = 0; mt < 2; mt++) {
            int mbase = m0 + wr * 32 + mt * 16 + lquad * 4;
#pragma unroll
            for (int r = 0; r < 4; r++)
                C[(size_t)(mbase + r) * N + n] = acc[mt][nt][r] + bv2;
        }
    }
}

// ---------------------------------------------------------------------------
extern "C" void kernel_launch(void* const* d_in, const int* in_sizes, int n_in,
                              void* d_out, int out_size, void* d_ws, size_t ws_size,
                              hipStream_t stream)
{
    const float* x  = (const float*)d_in[0];
    const float* Wq = (const float*)d_in[1];
    const float* Wk = (const float*)d_in[2];
    const float* Wv = (const float*)d_in[3];
    const float* Wo = (const float*)d_in[4];
    const float* bo = (const float*)d_in[5];
    float* out = (float*)d_out;

    f16* Xh  = (f16*)d_ws;             // 8388608 (X as f16) — dead after qkv_gemm
    f16* AO  = Xh;                     // alias: AO (2097152) reuses Xh region
    f16* Wqh = Xh  + 8388608;          // 1048576
    f16* Wkh = Wqh + 1048576;          // 1048576
    f16* Wvh = Wkh + 1048576;          // 1048576
    f16* Wr  = Wvh + 1048576;          // 1048576 (folded Wo)
    f16* Qws = Wr  + 1048576;          // 2097152 (B,4,S,D)
    f16* Kws = Qws + 2097152;          // 2097152
    f16* Vws = Kws + 2097152;          // 2097152 (B,4,D,S)
    // total 18,874,368 f16 = 36 MiB

    cvt_fold<<<dim3(12288), 256, 0, stream>>>(x, Wq, Wk, Wv, Wo, Xh, Wqh, Wkh, Wvh, Wr);
    qkv_gemm<<<dim3(4, 64, 3), 256, 0, stream>>>(Xh, Wqh, Wkh, Wvh, Qws, Kws, Vws);
    attn_win<<<dim3(128, 8), 64, 0, stream>>>(Qws, Kws, Vws, AO);
    out_gemm<<<dim3(16, 64), 256, 0, stream>>>(AO, Wr, bo, out);
}

// Round 4
// 202.499 us; speedup vs baseline: 1.0868x; 1.0868x over previous
//
#include <hip/hip_runtime.h>

typedef _Float16 f16;
typedef _Float16 f16x8 __attribute__((ext_vector_type(8)));
typedef _Float16 f16x4 __attribute__((ext_vector_type(4)));
typedef float    f32x4 __attribute__((ext_vector_type(4)));

// Problem: B=2, S=2048, E=2048, H=16, HKV=4, D=128, WINDOW=256
// Reference quirk: q is ALSO indexed by idx=repeat(arange(4),4) -> only q heads
// 0..3 (Wq rows 0..511) used; output head i = attn_{i//4}, so Wo pre-folds:
// Wr[e,g*128+d] = sum_j Wo[e,(4g+j)*128+d].
//
// R9: R3 post-mortem: dur pinned at 53.5us across 3 structures; staging
// gathers 16 rows x 64B at 4KB stride per DMA instruction -> bound by
// scattered-request throughput, not latency. Fix: PRE-PACKED operand layout.
//   - cvt_pack writes X/W/Wr as (panel, ktile) blocks: A-tile 64x32 f16 =
//     4KB contiguous, B-tile 128x32 = 8KB contiguous, chunk-swizzle BAKED IN
//     (packed[row][kc] = orig[row][kc ^ ((row>>1)&3)]). All GEMM DMA loads
//     become 1KB fully-linear; K-steps stream sequentially.
//   - qkv merged to one N=1536 GEMM (Wq'|Wk|Wv contiguous).
//   - attn writes AO directly in packed+swizzled layout for out_gemm.
//   - bijective XCD swizzle (768=8*96, 1024=8*128) so panel-sharing blocks
//     land on the same XCD L2.
//   - 4 LDS buffers, depth-3 prefetch, steady-state vmcnt(6), lgkmcnt(0)
//     pinned before each barrier (WAR hardening, rule #18).

__device__ __forceinline__ void load_lds16(const void* g, void* l) {
    __builtin_amdgcn_global_load_lds(
        (__attribute__((address_space(1))) void*)(g),
        (__attribute__((address_space(3))) void*)(l), 16, 0, 0);
}

// ---------------------------------------------------------------------------
// Pre-pass: f32->f16 convert + pack.
//  blk [0,4096):    X  -> Xp  (64 panels x 64 ktiles, tile 64x32)
//  blk [4096,5632): W  -> Wp  (12 panels x 64 ktiles, tile 128x32; rows
//                   0..511 Wq, 512..1023 Wk, 1024..1535 Wv)
//  blk [5632,6144): Wo -> Wrp (16 panels x 16 ktiles, tile 128x32, GQA-folded)
// One thread = one 16B output chunk (8 f16).
// ---------------------------------------------------------------------------
__global__ __launch_bounds__(256)
void cvt_pack(const float* __restrict__ X, const float* __restrict__ Wq,
              const float* __restrict__ Wk, const float* __restrict__ Wv,
              const float* __restrict__ Wo,
              f16* __restrict__ Xp, f16* __restrict__ Wp, f16* __restrict__ Wrp)
{
    const int blk = blockIdx.x, tid = threadIdx.x;
    if (blk < 4096) {
        int cid = blk * 256 + tid;            // < 1,048,576
        int tile = cid >> 8, wc = cid & 255;
        int row = wc >> 2, kc = wc & 3;
        int m = ((tile >> 6) << 6) + row;
        int t = tile & 63;
        int sk = t * 32 + ((kc ^ ((row >> 1) & 3)) << 3);
        const float* s = X + (size_t)m * 2048 + sk;
        float4 a = *(const float4*)(s);
        float4 b = *(const float4*)(s + 4);
        f16x8 o;
        o[0]=(f16)a.x; o[1]=(f16)a.y; o[2]=(f16)a.z; o[3]=(f16)a.w;
        o[4]=(f16)b.x; o[5]=(f16)b.y; o[6]=(f16)b.z; o[7]=(f16)b.w;
        *(f16x8*)(Xp + (size_t)cid * 8) = o;
    } else if (blk < 5632) {
        int wid = (blk - 4096) * 256 + tid;   // < 393,216
        int tile = wid >> 9, wc = wid & 511;
        int row = wc >> 2, kc = wc & 3;
        int n = ((tile >> 6) << 7) + row;
        int t = tile & 63;
        int sk = t * 32 + ((kc ^ ((row >> 1) & 3)) << 3);
        const float* src = (n < 512)  ? (Wq + (size_t)n * 2048 + sk)
                         : (n < 1024) ? (Wk + (size_t)(n - 512) * 2048 + sk)
                                      : (Wv + (size_t)(n - 1024) * 2048 + sk);
        float4 a = *(const float4*)(src);
        float4 b = *(const float4*)(src + 4);
        f16x8 o;
        o[0]=(f16)a.x; o[1]=(f16)a.y; o[2]=(f16)a.z; o[3]=(f16)a.w;
        o[4]=(f16)b.x; o[5]=(f16)b.y; o[6]=(f16)b.z; o[7]=(f16)b.w;
        *(f16x8*)(Wp + (size_t)wid * 8) = o;
    } else {
        int rid = (blk - 5632) * 256 + tid;   // < 131,072
        int tile = rid >> 9, wc = rid & 511;
        int row = wc >> 2, kc = wc & 3;
        int e = ((tile >> 4) << 7) + row;
        int t = tile & 15;
        int cc = kc ^ ((row >> 1) & 3);
        int c = t * 32 + (cc << 3);
        int g = c >> 7, d0 = c & 127;
        const float* src = Wo + (size_t)e * 2048 + g * 512 + d0;
        float4 a0 = *(const float4*)(src);
        float4 a1 = *(const float4*)(src + 128);
        float4 a2 = *(const float4*)(src + 256);
        float4 a3 = *(const float4*)(src + 384);
        float4 b0 = *(const float4*)(src + 4);
        float4 b1 = *(const float4*)(src + 132);
        float4 b2 = *(const float4*)(src + 260);
        float4 b3 = *(const float4*)(src + 388);
        f16x8 o;
        o[0] = (f16)(a0.x + a1.x + a2.x + a3.x);
        o[1] = (f16)(a0.y + a1.y + a2.y + a3.y);
        o[2] = (f16)(a0.z + a1.z + a2.z + a3.z);
        o[3] = (f16)(a0.w + a1.w + a2.w + a3.w);
        o[4] = (f16)(b0.x + b1.x + b2.x + b3.x);
        o[5] = (f16)(b0.y + b1.y + b2.y + b3.y);
        o[6] = (f16)(b0.z + b1.z + b2.z + b3.z);
        o[7] = (f16)(b0.w + b1.w + b2.w + b3.w);
        *(f16x8*)(Wrp + (size_t)rid * 8) = o;
    }
}

// Staging macro: 3 DMA loads per wave per K-step, fully-linear sources.
#define STAGE3(t, buf)                                          \
    {                                                           \
        load_lds16(gs0 + (size_t)(t) * st0, &S[buf][lo0]);      \
        load_lds16(gs1 + (size_t)(t) * st1, &S[buf][lo1]);      \
        load_lds16(gs2 + (size_t)(t) * st2, &S[buf][lo2]);      \
    }

#define PIPE_WAIT(t, NSTEP)                                              \
    if ((t) < (NSTEP)-2) {                                               \
        asm volatile("s_waitcnt vmcnt(6) lgkmcnt(0)" ::: "memory");      \
    } else if ((t) == (NSTEP)-2) {                                       \
        asm volatile("s_waitcnt vmcnt(3) lgkmcnt(0)" ::: "memory");      \
    } else {                                                             \
        asm volatile("s_waitcnt vmcnt(0) lgkmcnt(0)" ::: "memory");      \
    }                                                                    \
    __builtin_amdgcn_s_barrier();

// ---------------------------------------------------------------------------
// Merged QKV GEMM: C[m,n] = sum_k X[m,k]*W[n,k]; M=4096, N=1536, K=2048.
// Packed inputs. Tile 64x128, 4 waves (each 32x64). Grid 768 (12 x 64).
// n in [0,512): Q (B,4,S,D); [512,1024): K (B,4,S,D); [1024,1536): V (B,4,D,S).
// ---------------------------------------------------------------------------
__global__ __launch_bounds__(256)
void qkv_gemm(const f16* __restrict__ Xp, const f16* __restrict__ Wp,
              f16* __restrict__ Qo, f16* __restrict__ Ko, f16* __restrict__ Vo)
{
    const int NSTEP = 64;
    __shared__ __align__(16) f16 S[4][6144];

    const int tid = threadIdx.x;
    const int wave = tid >> 6, lane = tid & 63;
    const int lrow = lane & 15, lquad = lane >> 4;
    const int wr = wave >> 1, wc = wave & 1;

    int id = (int)blockIdx.x;                 // 768 = 8 * 96
    int id2 = (id & 7) * 96 + (id >> 3);      // bijective XCD swizzle
    int bx = id2 % 12, by = id2 / 12;
    const int m0 = by * 64, n0 = bx * 128;

    // wave staging slots: slot s=(wave*3+j)*64+lane; s<256 -> A, else B.
    const f16* gs0; const f16* gs1; const f16* gs2;
    size_t st0, st1, st2;
    int lo0, lo1, lo2;
    {
        int sb;
        sb = (wave * 3 + 0) * 64; lo0 = (sb + lane) * 8;
        if (sb < 256) { gs0 = Xp + (size_t)by * 131072 + lo0;          st0 = 2048; }
        else          { gs0 = Wp + (size_t)bx * 262144 + (lo0 - 2048); st0 = 4096; }
        sb = (wave * 3 + 1) * 64; lo1 = (sb + lane) * 8;
        if (sb < 256) { gs1 = Xp + (size_t)by * 131072 + lo1;          st1 = 2048; }
        else          { gs1 = Wp + (size_t)bx * 262144 + (lo1 - 2048); st1 = 4096; }
        sb = (wave * 3 + 2) * 64; lo2 = (sb + lane) * 8;
        if (sb < 256) { gs2 = Xp + (size_t)by * 131072 + lo2;          st2 = 2048; }
        else          { gs2 = Wp + (size_t)bx * 262144 + (lo2 - 2048); st2 = 4096; }
    }

    // swizzled fragment read offsets (f16 units); B region starts at 2048
    int aoff[2], boff[4];
#pragma unroll
    for (int t = 0; t < 2; t++) {
        int ra = wr * 32 + t * 16 + lrow;
        aoff[t] = ra * 32 + ((lquad ^ ((ra >> 1) & 3)) << 3);
    }
#pragma unroll
    for (int t = 0; t < 4; t++) {
        int rb = wc * 64 + t * 16 + lrow;
        boff[t] = 2048 + rb * 32 + ((lquad ^ ((rb >> 1) & 3)) << 3);
    }

    f32x4 acc[2][4];
    const f32x4 z4 = {0.f, 0.f, 0.f, 0.f};
#pragma unroll
    for (int i = 0; i < 2; i++) for (int j = 0; j < 4; j++) acc[i][j] = z4;

    STAGE3(0, 0); STAGE3(1, 1); STAGE3(2, 2);

    int buf = 0;
    for (int t = 0; t < NSTEP; ++t) {
        PIPE_WAIT(t, NSTEP);
        if (t < NSTEP - 3) STAGE3(t + 3, (buf + 3) & 3);
        f16x8 af[2], bf[4];
#pragma unroll
        for (int mt = 0; mt < 2; mt++) af[mt] = *(const f16x8*)(&S[buf][aoff[mt]]);
#pragma unroll
        for (int nt = 0; nt < 4; nt++) bf[nt] = *(const f16x8*)(&S[buf][boff[nt]]);
#pragma unroll
        for (int mt = 0; mt < 2; mt++)
#pragma unroll
            for (int nt = 0; nt < 4; nt++)
                acc[mt][nt] = __builtin_amdgcn_mfma_f32_16x16x32_f16(af[mt], bf[nt], acc[mt][nt], 0, 0, 0);
        buf = (buf + 1) & 3;
    }

    const int z = n0 >> 9;
    const int hh = (n0 >> 7) & 3;
    if (z < 2) {
        f16* C = z ? Ko : Qo;
#pragma unroll
        for (int mt = 0; mt < 2; mt++) {
            int mbase = m0 + wr * 32 + mt * 16 + lquad * 4;
#pragma unroll
            for (int r = 0; r < 4; r++) {
                int m = mbase + r;
                int bb = m >> 11, s = m & 2047;
#pragma unroll
                for (int nt = 0; nt < 4; nt++) {
                    int d = wc * 64 + nt * 16 + lrow;
                    C[(size_t)(((bb * 4 + hh) << 11) + s) * 128 + d] = (f16)acc[mt][nt][r];
                }
            }
        }
    } else {
#pragma unroll
        for (int mt = 0; mt < 2; mt++) {
            int mbase = m0 + wr * 32 + mt * 16 + lquad * 4;
            int bb = mbase >> 11, s = mbase & 2047;
#pragma unroll
            for (int nt = 0; nt < 4; nt++) {
                int d = wc * 64 + nt * 16 + lrow;
                f16x4 pk;
#pragma unroll
                for (int r = 0; r < 4; r++) pk[r] = (f16)acc[mt][nt][r];
                *(f16x4*)(Vo + ((size_t)((bb * 4 + hh) * 128 + d) << 11) + s) = pk;
            }
        }
    }
}

// ---------------------------------------------------------------------------
// Sliding-window attention, one wave per 16 query rows.
// Q,K: (B,4,S,D); V: (B,4,D,S) transposed.
// AO written directly in out_gemm's packed+swizzled A layout.
// ---------------------------------------------------------------------------
__global__ __launch_bounds__(64)
void attn_win(const f16* __restrict__ Q, const f16* __restrict__ Kc,
              const f16* __restrict__ Vt, f16* __restrict__ AO)
{
    const int bg = blockIdx.y;
    const int b = bg >> 2, g = bg & 3;
    const int qbase = blockIdx.x * 16;
    const int lane = threadIdx.x;
    const int lrow = lane & 15, lquad = lane >> 4;

    const f16* Qb = Q  + (size_t)(b * 4 + g) * (2048 * 128);
    const f16* Kb = Kc + (size_t)(b * 4 + g) * (2048 * 128);
    const f16* Vb = Vt + (size_t)(b * 4 + g) * (128 * 2048);

    __shared__ __align__(16) f16 Pl[16 * 128];

    f16x8 qf[4];
    for (int ks = 0; ks < 4; ks++)
        qf[ks] = *(const f16x8*)(Qb + (size_t)(qbase + lrow) * 128 + ks * 32 + lquad * 8);

    float m_i[4], l_i[4];
    f32x4 oa[8];
    const f32x4 z4 = {0.f, 0.f, 0.f, 0.f};
    for (int r = 0; r < 4; r++) { m_i[r] = -30000.f; l_i[r] = 0.f; }
    for (int nt = 0; nt < 8; nt++) oa[nt] = z4;

    const int t0 = (qbase >= 256) ? (((qbase - 255) >> 7) << 7) : 0;
    for (int kt = t0; kt <= qbase + 15; kt += 128) {
        f32x4 sc[8];
        for (int nt = 0; nt < 8; nt++) sc[nt] = z4;
        for (int nt = 0; nt < 8; nt++) {
            for (int ks = 0; ks < 4; ks++) {
                f16x8 kf = *(const f16x8*)(Kb + (size_t)(kt + nt * 16 + lrow) * 128 + ks * 32 + lquad * 8);
                sc[nt] = __builtin_amdgcn_mfma_f32_16x16x32_f16(qf[ks], kf, sc[nt], 0, 0, 0);
            }
        }
        for (int r = 0; r < 4; r++) {
            const int qi = qbase + lquad * 4 + r;
            float rmax = -60000.f;
            for (int nt = 0; nt < 8; nt++) {
                int kj = kt + nt * 16 + lrow;
                float sval = sc[nt][r];
                bool ok = (kj <= qi) && (kj + 256 > qi);
                sval = ok ? sval : -60000.f;
                sc[nt][r] = sval;
                rmax = fmaxf(rmax, sval);
            }
            rmax = fmaxf(rmax, __shfl_xor(rmax, 1));
            rmax = fmaxf(rmax, __shfl_xor(rmax, 2));
            rmax = fmaxf(rmax, __shfl_xor(rmax, 4));
            rmax = fmaxf(rmax, __shfl_xor(rmax, 8));
            float mold = m_i[r];
            float mnew = fmaxf(mold, rmax);
            float alpha = __expf(mold - mnew);
            m_i[r] = mnew;
            float rsum = 0.f;
            for (int nt = 0; nt < 8; nt++) {
                float p = __expf(sc[nt][r] - mnew);
                sc[nt][r] = p;
                rsum += p;
            }
            rsum += __shfl_xor(rsum, 1);
            rsum += __shfl_xor(rsum, 2);
            rsum += __shfl_xor(rsum, 4);
            rsum += __shfl_xor(rsum, 8);
            l_i[r] = l_i[r] * alpha + rsum;
            for (int nt = 0; nt < 8; nt++) oa[nt][r] *= alpha;
        }
        for (int nt = 0; nt < 8; nt++)
            for (int r = 0; r < 4; r++)
                Pl[(lquad * 4 + r) * 128 + nt * 16 + lrow] = (f16)sc[nt][r];
        __syncthreads();
        f16x8 pf[4];
        for (int ks = 0; ks < 4; ks++)
            pf[ks] = *(const f16x8*)(Pl + lrow * 128 + ks * 32 + lquad * 8);
        for (int nt = 0; nt < 8; nt++) {
            for (int ks = 0; ks < 4; ks++) {
                f16x8 vf = *(const f16x8*)(Vb + (size_t)(nt * 16 + lrow) * 2048 + kt + ks * 32 + lquad * 8);
                oa[nt] = __builtin_amdgcn_mfma_f32_16x16x32_f16(pf[ks], vf, oa[nt], 0, 0, 0);
            }
        }
        __syncthreads();
    }
    float inv[4];
    for (int r = 0; r < 4; r++) inv[r] = (l_i[r] > 0.f) ? 1.f / l_i[r] : 0.f;
    for (int nt = 0; nt < 8; nt++) {
        for (int r = 0; r < 4; r++) {
            int q = qbase + lquad * 4 + r;
            int d = nt * 16 + lrow;
            int m = b * 2048 + q;
            int col = g * 128 + d;
            int p = m >> 6, r2 = m & 63;
            int t = col >> 5;
            int cc = (col >> 3) & 3;
            size_t off = (((size_t)p * 16 + t) * 64 + r2) * 32
                       + ((cc ^ ((r2 >> 1) & 3)) << 3) + (col & 7);
            AO[off] = (f16)(oa[nt][r] * inv[r]);
        }
    }
}

// ---------------------------------------------------------------------------
// Output GEMM: out = AO @ Wr^T + bo, f32 out. M=4096, N=2048, K=512.
// Packed inputs (AO: 64x16 tiles of 64x32; Wrp: 16x16 tiles of 128x32).
// Grid 1024 (16 x 64), same pipeline as qkv_gemm.
// ---------------------------------------------------------------------------
__global__ __launch_bounds__(256)
void out_gemm(const f16* __restrict__ Ap, const f16* __restrict__ Bp,
              const float* __restrict__ bias, float* __restrict__ C)
{
    const int NSTEP = 16, N = 2048;
    __shared__ __align__(16) f16 S[4][6144];

    const int tid = threadIdx.x;
    const int wave = tid >> 6, lane = tid & 63;
    const int lrow = lane & 15, lquad = lane >> 4;
    const int wr = wave >> 1, wc = wave & 1;

    int id = (int)blockIdx.x;                 // 1024 = 8 * 128
    int id2 = (id & 7) * 128 + (id >> 3);
    int bx = id2 & 15, by = id2 >> 4;
    const int m0 = by * 64, n0 = bx * 128;

    const f16* gs0; const f16* gs1; const f16* gs2;
    size_t st0, st1, st2;
    int lo0, lo1, lo2;
    {
        int sb;
        sb = (wave * 3 + 0) * 64; lo0 = (sb + lane) * 8;
        if (sb < 256) { gs0 = Ap + (size_t)by * 32768 + lo0;          st0 = 2048; }
        else          { gs0 = Bp + (size_t)bx * 65536 + (lo0 - 2048); st0 = 4096; }
        sb = (wave * 3 + 1) * 64; lo1 = (sb + lane) * 8;
        if (sb < 256) { gs1 = Ap + (size_t)by * 32768 + lo1;          st1 = 2048; }
        else          { gs1 = Bp + (size_t)bx * 65536 + (lo1 - 2048); st1 = 4096; }
        sb = (wave * 3 + 2) * 64; lo2 = (sb + lane) * 8;
        if (sb < 256) { gs2 = Ap + (size_t)by * 32768 + lo2;          st2 = 2048; }
        else          { gs2 = Bp + (size_t)bx * 65536 + (lo2 - 2048); st2 = 4096; }
    }

    int aoff[2], boff[4];
#pragma unroll
    for (int t = 0; t < 2; t++) {
        int ra = wr * 32 + t * 16 + lrow;
        aoff[t] = ra * 32 + ((lquad ^ ((ra >> 1) & 3)) << 3);
    }
#pragma unroll
    for (int t = 0; t < 4; t++) {
        int rb = wc * 64 + t * 16 + lrow;
        boff[t] = 2048 + rb * 32 + ((lquad ^ ((rb >> 1) & 3)) << 3);
    }

    f32x4 acc[2][4];
    const f32x4 z4 = {0.f, 0.f, 0.f, 0.f};
#pragma unroll
    for (int i = 0; i < 2; i++) for (int j = 0; j < 4; j++) acc[i][j] = z4;

    STAGE3(0, 0); STAGE3(1, 1); STAGE3(2, 2);

    int buf = 0;
    for (int t = 0; t < NSTEP; ++t) {
        PIPE_WAIT(t, NSTEP);
        if (t < NSTEP - 3) STAGE3(t + 3, (buf + 3) & 3);
        f16x8 af[2], bf[4];
#pragma unroll
        for (int mt = 0; mt < 2; mt++) af[mt] = *(const f16x8*)(&S[buf][aoff[mt]]);
#pragma unroll
        for (int nt = 0; nt < 4; nt++) bf[nt] = *(const f16x8*)(&S[buf][boff[nt]]);
#pragma unroll
        for (int mt = 0; mt < 2; mt++)
#pragma unroll
            for (int nt = 0; nt < 4; nt++)
                acc[mt][nt] = __builtin_amdgcn_mfma_f32_16x16x32_f16(af[mt], bf[nt], acc[mt][nt], 0, 0, 0);
        buf = (buf + 1) & 3;
    }

#pragma unroll
    for (int nt = 0; nt < 4; nt++) {
        int n = n0 + wc * 64 + nt * 16 + lrow;
        float bv2 = bias[n];
#pragma unroll
        for (int mt = 0; mt < 2; mt++) {
            int mbase = m0 + wr * 32 + mt * 16 + lquad * 4;
#pragma unroll
            for (int r = 0; r < 4; r++)
                C[(size_t)(mbase + r) * N + n] = acc[mt][nt][r] + bv2;
        }
    }
}

// ---------------------------------------------------------------------------
extern "C" void kernel_launch(void* const* d_in, const int* in_sizes, int n_in,
                              void* d_out, int out_size, void* d_ws, size_t ws_size,
                              hipStream_t stream)
{
    const float* x  = (const float*)d_in[0];
    const float* Wq = (const float*)d_in[1];
    const float* Wk = (const float*)d_in[2];
    const float* Wv = (const float*)d_in[3];
    const float* Wo = (const float*)d_in[4];
    const float* bo = (const float*)d_in[5];
    float* out = (float*)d_out;

    f16* Xp  = (f16*)d_ws;             // 8,388,608 (packed X) — dead after qkv
    f16* AO  = Xp;                     // alias: packed AO (2,097,152) reuses Xp
    f16* Wp  = Xp  + 8388608;          // 3,145,728 (packed Wq'|Wk|Wv)
    f16* Wrp = Wp  + 3145728;          // 1,048,576 (packed folded Wo)
    f16* Qws = Wrp + 1048576;          // 2,097,152 (B,4,S,D)
    f16* Kws = Qws + 2097152;          // 2,097,152
    f16* Vws = Kws + 2097152;          // 2,097,152 (B,4,D,S)
    // total 18,874,368 f16 = 36 MiB (same as before)

    cvt_pack<<<dim3(6144), 256, 0, stream>>>(x, Wq, Wk, Wv, Wo, Xp, Wp, Wrp);
    qkv_gemm<<<dim3(768), 256, 0, stream>>>(Xp, Wp, Qws, Kws, Vws);
    attn_win<<<dim3(128, 8), 64, 0, stream>>>(Qws, Kws, Vws, AO);
    out_gemm<<<dim3(1024), 256, 0, stream>>>(AO, Wrp, bo, out);
}

// Round 6
// 177.671 us; speedup vs baseline: 1.2387x; 1.1397x over previous
//
#include <hip/hip_runtime.h>

typedef _Float16 f16;
typedef _Float16 f16x8 __attribute__((ext_vector_type(8)));
typedef _Float16 f16x4 __attribute__((ext_vector_type(4)));
typedef float    f32x4 __attribute__((ext_vector_type(4)));

// Problem: B=2, S=2048, E=2048, H=16, HKV=4, D=128, WINDOW=256
// Reference quirk: only q heads 0..3 used (q also indexed by idx); Wo pre-folds
// over the 4 heads per group: Wr[e,g*128+d] = sum_j Wo[e,(4g+j)*128+d].
//
// R11 = R10 resubmit (container failed twice; audit found no defect —
// barriers uniform, DMA dest = base+lane*16B, all bounds checked, pipeline
// vmcnt invariant verified; R2 precedent: same failure, retry passed).
//  - qkv epilogue writes K,V in attn-packed 32KB tiles (128 keys x 128 dims,
//    granule-swizzled gran^(row&15)), so attn stages them as LINEAR DMA.
//  - attn: 4 waves/block, 64 q-rows, K/V tiles double-buffered in LDS via
//    global_load_lds, counted vmcnt(16); swizzled ds_read_b128 fragments.
//  - bg = blockIdx.x & 7 pins each (b,g) head to one XCD -> K/V served from
//    that XCD's L2 across its 32 q-blocks.

__device__ __forceinline__ void load_lds16(const void* g, void* l) {
    __builtin_amdgcn_global_load_lds(
        (__attribute__((address_space(1))) void*)(g),
        (__attribute__((address_space(3))) void*)(l), 16, 0, 0);
}

// ---------------------------------------------------------------------------
// Pre-pass: f32->f16 convert + pack.
//  blk [0,4096):    X  -> Xp  (64 panels x 64 ktiles, tile 64x32)
//  blk [4096,5632): W  -> Wp  (12 panels x 64 ktiles, tile 128x32)
//  blk [5632,6144): Wo -> Wrp (16 panels x 16 ktiles, tile 128x32, GQA-folded)
// ---------------------------------------------------------------------------
__global__ __launch_bounds__(256)
void cvt_pack(const float* __restrict__ X, const float* __restrict__ Wq,
              const float* __restrict__ Wk, const float* __restrict__ Wv,
              const float* __restrict__ Wo,
              f16* __restrict__ Xp, f16* __restrict__ Wp, f16* __restrict__ Wrp)
{
    const int blk = blockIdx.x, tid = threadIdx.x;
    if (blk < 4096) {
        int cid = blk * 256 + tid;
        int tile = cid >> 8, wc = cid & 255;
        int row = wc >> 2, kc = wc & 3;
        int m = ((tile >> 6) << 6) + row;
        int t = tile & 63;
        int sk = t * 32 + ((kc ^ ((row >> 1) & 3)) << 3);
        const float* s = X + (size_t)m * 2048 + sk;
        float4 a = *(const float4*)(s);
        float4 b = *(const float4*)(s + 4);
        f16x8 o;
        o[0]=(f16)a.x; o[1]=(f16)a.y; o[2]=(f16)a.z; o[3]=(f16)a.w;
        o[4]=(f16)b.x; o[5]=(f16)b.y; o[6]=(f16)b.z; o[7]=(f16)b.w;
        *(f16x8*)(Xp + (size_t)cid * 8) = o;
    } else if (blk < 5632) {
        int wid = (blk - 4096) * 256 + tid;
        int tile = wid >> 9, wc = wid & 511;
        int row = wc >> 2, kc = wc & 3;
        int n = ((tile >> 6) << 7) + row;
        int t = tile & 63;
        int sk = t * 32 + ((kc ^ ((row >> 1) & 3)) << 3);
        const float* src = (n < 512)  ? (Wq + (size_t)n * 2048 + sk)
                         : (n < 1024) ? (Wk + (size_t)(n - 512) * 2048 + sk)
                                      : (Wv + (size_t)(n - 1024) * 2048 + sk);
        float4 a = *(const float4*)(src);
        float4 b = *(const float4*)(src + 4);
        f16x8 o;
        o[0]=(f16)a.x; o[1]=(f16)a.y; o[2]=(f16)a.z; o[3]=(f16)a.w;
        o[4]=(f16)b.x; o[5]=(f16)b.y; o[6]=(f16)b.z; o[7]=(f16)b.w;
        *(f16x8*)(Wp + (size_t)wid * 8) = o;
    } else {
        int rid = (blk - 5632) * 256 + tid;
        int tile = rid >> 9, wc = rid & 511;
        int row = wc >> 2, kc = wc & 3;
        int e = ((tile >> 4) << 7) + row;
        int t = tile & 15;
        int cc = kc ^ ((row >> 1) & 3);
        int c = t * 32 + (cc << 3);
        int g = c >> 7, d0 = c & 127;
        const float* src = Wo + (size_t)e * 2048 + g * 512 + d0;
        float4 a0 = *(const float4*)(src);
        float4 a1 = *(const float4*)(src + 128);
        float4 a2 = *(const float4*)(src + 256);
        float4 a3 = *(const float4*)(src + 384);
        float4 b0 = *(const float4*)(src + 4);
        float4 b1 = *(const float4*)(src + 132);
        float4 b2 = *(const float4*)(src + 260);
        float4 b3 = *(const float4*)(src + 388);
        f16x8 o;
        o[0] = (f16)(a0.x + a1.x + a2.x + a3.x);
        o[1] = (f16)(a0.y + a1.y + a2.y + a3.y);
        o[2] = (f16)(a0.z + a1.z + a2.z + a3.z);
        o[3] = (f16)(a0.w + a1.w + a2.w + a3.w);
        o[4] = (f16)(b0.x + b1.x + b2.x + b3.x);
        o[5] = (f16)(b0.y + b1.y + b2.y + b3.y);
        o[6] = (f16)(b0.z + b1.z + b2.z + b3.z);
        o[7] = (f16)(b0.w + b1.w + b2.w + b3.w);
        *(f16x8*)(Wrp + (size_t)rid * 8) = o;
    }
}

#define STAGE3(t, buf)                                          \
    {                                                           \
        load_lds16(gs0 + (size_t)(t) * st0, &S[buf][lo0]);      \
        load_lds16(gs1 + (size_t)(t) * st1, &S[buf][lo1]);      \
        load_lds16(gs2 + (size_t)(t) * st2, &S[buf][lo2]);      \
    }

#define PIPE_WAIT(t, NSTEP)                                              \
    if ((t) < (NSTEP)-2) {                                               \
        asm volatile("s_waitcnt vmcnt(6) lgkmcnt(0)" ::: "memory");      \
    } else if ((t) == (NSTEP)-2) {                                       \
        asm volatile("s_waitcnt vmcnt(3) lgkmcnt(0)" ::: "memory");      \
    } else {                                                             \
        asm volatile("s_waitcnt vmcnt(0) lgkmcnt(0)" ::: "memory");      \
    }                                                                    \
    __builtin_amdgcn_s_barrier();

// ---------------------------------------------------------------------------
// Merged QKV GEMM: M=4096, N=1536, K=2048. Packed inputs. Tile 64x128.
// n in [0,512): Q -> (B,4,S,D); [512,1024): K -> attn-packed tiles;
// [1024,1536): V -> attn-packed tiles.
// Packed K:  Kp[bg][t][s&127][ ((d>>3)^(s&15))*8 + (d&7) ]
// Packed V:  Vp[bg][t][d]    [ ((s7>>3)^(d&15))*8 + (s7&7) ]  (s7 = s&127)
// ---------------------------------------------------------------------------
__global__ __launch_bounds__(256)
void qkv_gemm(const f16* __restrict__ Xp, const f16* __restrict__ Wp,
              f16* __restrict__ Qo, f16* __restrict__ Ko, f16* __restrict__ Vo)
{
    const int NSTEP = 64;
    __shared__ __align__(16) f16 S[4][6144];

    const int tid = threadIdx.x;
    const int wave = tid >> 6, lane = tid & 63;
    const int lrow = lane & 15, lquad = lane >> 4;
    const int wr = wave >> 1, wc = wave & 1;

    int id = (int)blockIdx.x;                 // 768 = 8 * 96
    int id2 = (id & 7) * 96 + (id >> 3);      // bijective XCD swizzle
    int bx = id2 % 12, by = id2 / 12;
    const int m0 = by * 64, n0 = bx * 128;

    const f16* gs0; const f16* gs1; const f16* gs2;
    size_t st0, st1, st2;
    int lo0, lo1, lo2;
    {
        int sb;
        sb = (wave * 3 + 0) * 64; lo0 = (sb + lane) * 8;
        if (sb < 256) { gs0 = Xp + (size_t)by * 131072 + lo0;          st0 = 2048; }
        else          { gs0 = Wp + (size_t)bx * 262144 + (lo0 - 2048); st0 = 4096; }
        sb = (wave * 3 + 1) * 64; lo1 = (sb + lane) * 8;
        if (sb < 256) { gs1 = Xp + (size_t)by * 131072 + lo1;          st1 = 2048; }
        else          { gs1 = Wp + (size_t)bx * 262144 + (lo1 - 2048); st1 = 4096; }
        sb = (wave * 3 + 2) * 64; lo2 = (sb + lane) * 8;
        if (sb < 256) { gs2 = Xp + (size_t)by * 131072 + lo2;          st2 = 2048; }
        else          { gs2 = Wp + (size_t)bx * 262144 + (lo2 - 2048); st2 = 4096; }
    }

    int aoff[2], boff[4];
#pragma unroll
    for (int t = 0; t < 2; t++) {
        int ra = wr * 32 + t * 16 + lrow;
        aoff[t] = ra * 32 + ((lquad ^ ((ra >> 1) & 3)) << 3);
    }
#pragma unroll
    for (int t = 0; t < 4; t++) {
        int rb = wc * 64 + t * 16 + lrow;
        boff[t] = 2048 + rb * 32 + ((lquad ^ ((rb >> 1) & 3)) << 3);
    }

    f32x4 acc[2][4];
    const f32x4 z4 = {0.f, 0.f, 0.f, 0.f};
#pragma unroll
    for (int i = 0; i < 2; i++) for (int j = 0; j < 4; j++) acc[i][j] = z4;

    STAGE3(0, 0); STAGE3(1, 1); STAGE3(2, 2);

    int buf = 0;
    for (int t = 0; t < NSTEP; ++t) {
        PIPE_WAIT(t, NSTEP);
        if (t < NSTEP - 3) STAGE3(t + 3, (buf + 3) & 3);
        f16x8 af[2], bf[4];
#pragma unroll
        for (int mt = 0; mt < 2; mt++) af[mt] = *(const f16x8*)(&S[buf][aoff[mt]]);
#pragma unroll
        for (int nt = 0; nt < 4; nt++) bf[nt] = *(const f16x8*)(&S[buf][boff[nt]]);
#pragma unroll
        for (int mt = 0; mt < 2; mt++)
#pragma unroll
            for (int nt = 0; nt < 4; nt++)
                acc[mt][nt] = __builtin_amdgcn_mfma_f32_16x16x32_f16(af[mt], bf[nt], acc[mt][nt], 0, 0, 0);
        buf = (buf + 1) & 3;
    }

    const int z = n0 >> 9;
    const int hh = (n0 >> 7) & 3;
    if (z == 0) {
        // Q: (B,4,S,D) row-major
#pragma unroll
        for (int mt = 0; mt < 2; mt++) {
            int mbase = m0 + wr * 32 + mt * 16 + lquad * 4;
#pragma unroll
            for (int r = 0; r < 4; r++) {
                int m = mbase + r;
                int bb = m >> 11, s = m & 2047;
#pragma unroll
                for (int nt = 0; nt < 4; nt++) {
                    int d = wc * 64 + nt * 16 + lrow;
                    Qo[(size_t)(((bb * 4 + hh) << 11) + s) * 128 + d] = (f16)acc[mt][nt][r];
                }
            }
        }
    } else if (z == 1) {
        // K: attn-packed swizzled tiles
#pragma unroll
        for (int mt = 0; mt < 2; mt++) {
            int mbase = m0 + wr * 32 + mt * 16 + lquad * 4;
#pragma unroll
            for (int r = 0; r < 4; r++) {
                int m = mbase + r;
                int bb = m >> 11, s = m & 2047;
                size_t base = ((size_t)(bb * 4 + hh) * 16 + (s >> 7)) * 16384
                            + (size_t)(s & 127) * 128;
#pragma unroll
                for (int nt = 0; nt < 4; nt++) {
                    int d = wc * 64 + nt * 16 + lrow;
                    Ko[base + (((d >> 3) ^ (s & 15)) << 3) + (d & 7)] = (f16)acc[mt][nt][r];
                }
            }
        }
    } else {
        // V: attn-packed swizzled tiles (f16x4 over 4 consecutive s)
#pragma unroll
        for (int mt = 0; mt < 2; mt++) {
            int mbase = m0 + wr * 32 + mt * 16 + lquad * 4;
            int bb = mbase >> 11, s = mbase & 2047;
            int tt = s >> 7, sl = s & 127;
            int gsx = sl >> 3, j0 = sl & 7;     // j0 in {0,4}; granule-constant
#pragma unroll
            for (int nt = 0; nt < 4; nt++) {
                int d = wc * 64 + nt * 16 + lrow;
                f16x4 pk;
#pragma unroll
                for (int r = 0; r < 4; r++) pk[r] = (f16)acc[mt][nt][r];
                *(f16x4*)(Vo + ((size_t)(bb * 4 + hh) * 16 + tt) * 16384
                             + (size_t)d * 128 + ((gsx ^ (d & 15)) << 3) + j0) = pk;
            }
        }
    }
}

// ---------------------------------------------------------------------------
// Sliding-window attention. 4 waves/block, 64 q-rows/block, one (b,g).
// Grid 256; bg = blockIdx.x & 7 pins each head to one XCD.
// K/V: packed swizzled 32KB tiles, staged as linear DMA, double-buffered.
// AO written in out_gemm's packed A layout.
// ---------------------------------------------------------------------------
__global__ __launch_bounds__(256)
void attn_win(const f16* __restrict__ Q, const f16* __restrict__ Kp,
              const f16* __restrict__ Vp, f16* __restrict__ AO)
{
    const int h = blockIdx.x;
    const int bg = h & 7, qt = h >> 3;
    const int b = bg >> 2, g = bg & 3;
    const int qbase = qt * 64;
    const int tid = threadIdx.x;
    const int wave = tid >> 6, lane = tid & 63;
    const int lrow = lane & 15, lquad = lane >> 4;
    const int qw = qbase + wave * 16;

    const f16* Qb = Q  + (size_t)bg * (2048 * 128);
    const f16* Kt = Kp + (size_t)bg * (2048 * 128);
    const f16* Vt = Vp + (size_t)bg * (2048 * 128);

    __shared__ __align__(16) f16 Ks[2][16384];
    __shared__ __align__(16) f16 Vs[2][16384];
    __shared__ __align__(16) f16 Pl[4][2048];

    f16x8 qf[4];
#pragma unroll
    for (int ks = 0; ks < 4; ks++)
        qf[ks] = *(const f16x8*)(Qb + (size_t)(qw + lrow) * 128 + ks * 32 + lquad * 8);

    float m_i[4], l_i[4];
    f32x4 oa[8];
    const f32x4 z4 = {0.f, 0.f, 0.f, 0.f};
#pragma unroll
    for (int r = 0; r < 4; r++) { m_i[r] = -30000.f; l_i[r] = 0.f; }
#pragma unroll
    for (int nt = 0; nt < 8; nt++) oa[nt] = z4;

    const int tstart = (qbase >= 256) ? ((qbase - 255) >> 7) : 0;
    const int tend = (qbase + 63) >> 7;

    {   // prologue: stage tile tstart into buf 0 (32 linear DMA instrs)
        const f16* ksrc = Kt + (size_t)tstart * 16384;
        const f16* vsrc = Vt + (size_t)tstart * 16384;
#pragma unroll
        for (int j = 0; j < 8; j++) {
            load_lds16(ksrc + (j * 256 + tid) * 8, &Ks[0][(j * 256 + tid) * 8]);
            load_lds16(vsrc + (j * 256 + tid) * 8, &Vs[0][(j * 256 + tid) * 8]);
        }
    }

    int buf = 0;
    for (int t = tstart; t <= tend; ++t) {
        if (t < tend) {       // prefetch next tile into other buffer
            const f16* ksrc = Kt + (size_t)(t + 1) * 16384;
            const f16* vsrc = Vt + (size_t)(t + 1) * 16384;
#pragma unroll
            for (int j = 0; j < 8; j++) {
                load_lds16(ksrc + (j * 256 + tid) * 8, &Ks[buf ^ 1][(j * 256 + tid) * 8]);
                load_lds16(vsrc + (j * 256 + tid) * 8, &Vs[buf ^ 1][(j * 256 + tid) * 8]);
            }
            asm volatile("s_waitcnt vmcnt(16)" ::: "memory");  // tile t ready
        } else {
            asm volatile("s_waitcnt vmcnt(0)" ::: "memory");
        }
        __builtin_amdgcn_s_barrier();

        const int kt = t * 128;
        f32x4 sc[8];
#pragma unroll
        for (int nt = 0; nt < 8; nt++) sc[nt] = z4;
#pragma unroll
        for (int nt = 0; nt < 8; nt++) {
#pragma unroll
            for (int ks = 0; ks < 4; ks++) {
                f16x8 kf = *(const f16x8*)(&Ks[buf][(nt * 16 + lrow) * 128
                                  + (((ks * 4 + lquad) ^ lrow) << 3)]);
                sc[nt] = __builtin_amdgcn_mfma_f32_16x16x32_f16(qf[ks], kf, sc[nt], 0, 0, 0);
            }
        }
#pragma unroll
        for (int r = 0; r < 4; r++) {
            const int qi = qw + lquad * 4 + r;
            float rmax = -60000.f;
#pragma unroll
            for (int nt = 0; nt < 8; nt++) {
                int kj = kt + nt * 16 + lrow;
                float sval = sc[nt][r];
                bool ok = (kj <= qi) && (kj + 256 > qi);
                sval = ok ? sval : -60000.f;
                sc[nt][r] = sval;
                rmax = fmaxf(rmax, sval);
            }
            rmax = fmaxf(rmax, __shfl_xor(rmax, 1));
            rmax = fmaxf(rmax, __shfl_xor(rmax, 2));
            rmax = fmaxf(rmax, __shfl_xor(rmax, 4));
            rmax = fmaxf(rmax, __shfl_xor(rmax, 8));
            float mold = m_i[r];
            float mnew = fmaxf(mold, rmax);
            float alpha = __expf(mold - mnew);
            m_i[r] = mnew;
            float rsum = 0.f;
#pragma unroll
            for (int nt = 0; nt < 8; nt++) {
                float p = __expf(sc[nt][r] - mnew);
                sc[nt][r] = p;
                rsum += p;
            }
            rsum += __shfl_xor(rsum, 1);
            rsum += __shfl_xor(rsum, 2);
            rsum += __shfl_xor(rsum, 4);
            rsum += __shfl_xor(rsum, 8);
            l_i[r] = l_i[r] * alpha + rsum;
#pragma unroll
            for (int nt = 0; nt < 8; nt++) oa[nt][r] *= alpha;
        }
        // P -> per-wave LDS slab, swizzled (write then read, same wave: DS
        // ops are in-order per wave).
#pragma unroll
        for (int nt = 0; nt < 8; nt++)
#pragma unroll
            for (int r = 0; r < 4; r++) {
                int row = lquad * 4 + r;
                int col = nt * 16 + lrow;
                Pl[wave][row * 128 + (((col >> 3) ^ row) << 3) + (col & 7)] = (f16)sc[nt][r];
            }
        f16x8 pf[4];
#pragma unroll
        for (int ks = 0; ks < 4; ks++)
            pf[ks] = *(const f16x8*)(&Pl[wave][lrow * 128
                              + (((ks * 4 + lquad) ^ lrow) << 3)]);
#pragma unroll
        for (int nt = 0; nt < 8; nt++) {
#pragma unroll
            for (int ks = 0; ks < 4; ks++) {
                f16x8 vf = *(const f16x8*)(&Vs[buf][(nt * 16 + lrow) * 128
                                  + (((ks * 4 + lquad) ^ lrow) << 3)]);
                oa[nt] = __builtin_amdgcn_mfma_f32_16x16x32_f16(pf[ks], vf, oa[nt], 0, 0, 0);
            }
        }
        asm volatile("s_waitcnt lgkmcnt(0)" ::: "memory");  // reads retired (WAR)
        __builtin_amdgcn_s_barrier();
        buf ^= 1;
    }

    float inv[4];
#pragma unroll
    for (int r = 0; r < 4; r++) inv[r] = (l_i[r] > 0.f) ? 1.f / l_i[r] : 0.f;
#pragma unroll
    for (int nt = 0; nt < 8; nt++) {
#pragma unroll
        for (int r = 0; r < 4; r++) {
            int q = qw + lquad * 4 + r;
            int d = nt * 16 + lrow;
            int m = b * 2048 + q;
            int col = g * 128 + d;
            int p = m >> 6, r2 = m & 63;
            int tt = col >> 5;
            int cc = (col >> 3) & 3;
            size_t off = (((size_t)p * 16 + tt) * 64 + r2) * 32
                       + ((cc ^ ((r2 >> 1) & 3)) << 3) + (col & 7);
            AO[off] = (f16)(oa[nt][r] * inv[r]);
        }
    }
}

// ---------------------------------------------------------------------------
// Output GEMM: out = AO @ Wr^T + bo, f32 out. M=4096, N=2048, K=512.
// Packed inputs; grid 1024 (16 x 64).
// ---------------------------------------------------------------------------
__global__ __launch_bounds__(256)
void out_gemm(const f16* __restrict__ Ap, const f16* __restrict__ Bp,
              const float* __restrict__ bias, float* __restrict__ C)
{
    const int NSTEP = 16, N = 2048;
    __shared__ __align__(16) f16 S[4][6144];

    const int tid = threadIdx.x;
    const int wave = tid >> 6, lane = tid & 63;
    const int lrow = lane & 15, lquad = lane >> 4;
    const int wr = wave >> 1, wc = wave & 1;

    int id = (int)blockIdx.x;                 // 1024 = 8 * 128
    int id2 = (id & 7) * 128 + (id >> 3);
    int bx = id2 & 15, by = id2 >> 4;
    const int m0 = by * 64, n0 = bx * 128;

    const f16* gs0; const f16* gs1; const f16* gs2;
    size_t st0, st1, st2;
    int lo0, lo1, lo2;
    {
        int sb;
        sb = (wave * 3 + 0) * 64; lo0 = (sb + lane) * 8;
        if (sb < 256) { gs0 = Ap + (size_t)by * 32768 + lo0;          st0 = 2048; }
        else          { gs0 = Bp + (size_t)bx * 65536 + (lo0 - 2048); st0 = 4096; }
        sb = (wave * 3 + 1) * 64; lo1 = (sb + lane) * 8;
        if (sb < 256) { gs1 = Ap + (size_t)by * 32768 + lo1;          st1 = 2048; }
        else          { gs1 = Bp + (size_t)bx * 65536 + (lo1 - 2048); st1 = 4096; }
        sb = (wave * 3 + 2) * 64; lo2 = (sb + lane) * 8;
        if (sb < 256) { gs2 = Ap + (size_t)by * 32768 + lo2;          st2 = 2048; }
        else          { gs2 = Bp + (size_t)bx * 65536 + (lo2 - 2048); st2 = 4096; }
    }

    int aoff[2], boff[4];
#pragma unroll
    for (int t = 0; t < 2; t++) {
        int ra = wr * 32 + t * 16 + lrow;
        aoff[t] = ra * 32 + ((lquad ^ ((ra >> 1) & 3)) << 3);
    }
#pragma unroll
    for (int t = 0; t < 4; t++) {
        int rb = wc * 64 + t * 16 + lrow;
        boff[t] = 2048 + rb * 32 + ((lquad ^ ((rb >> 1) & 3)) << 3);
    }

    f32x4 acc[2][4];
    const f32x4 z4 = {0.f, 0.f, 0.f, 0.f};
#pragma unroll
    for (int i = 0; i < 2; i++) for (int j = 0; j < 4; j++) acc[i][j] = z4;

    STAGE3(0, 0); STAGE3(1, 1); STAGE3(2, 2);

    int buf = 0;
    for (int t = 0; t < NSTEP; ++t) {
        PIPE_WAIT(t, NSTEP);
        if (t < NSTEP - 3) STAGE3(t + 3, (buf + 3) & 3);
        f16x8 af[2], bf[4];
#pragma unroll
        for (int mt = 0; mt < 2; mt++) af[mt] = *(const f16x8*)(&S[buf][aoff[mt]]);
#pragma unroll
        for (int nt = 0; nt < 4; nt++) bf[nt] = *(const f16x8*)(&S[buf][boff[nt]]);
#pragma unroll
        for (int mt = 0; mt < 2; mt++)
#pragma unroll
            for (int nt = 0; nt < 4; nt++)
                acc[mt][nt] = __builtin_amdgcn_mfma_f32_16x16x32_f16(af[mt], bf[nt], acc[mt][nt], 0, 0, 0);
        buf = (buf + 1) & 3;
    }

#pragma unroll
    for (int nt = 0; nt < 4; nt++) {
        int n = n0 + wc * 64 + nt * 16 + lrow;
        float bv2 = bias[n];
#pragma unroll
        for (int mt = 0; mt < 2; mt++) {
            int mbase = m0 + wr * 32 + mt * 16 + lquad * 4;
#pragma unroll
            for (int r = 0; r < 4; r++)
                C[(size_t)(mbase + r) * N + n] = acc[mt][nt][r] + bv2;
        }
    }
}

// ---------------------------------------------------------------------------
extern "C" void kernel_launch(void* const* d_in, const int* in_sizes, int n_in,
                              void* d_out, int out_size, void* d_ws, size_t ws_size,
                              hipStream_t stream)
{
    const float* x  = (const float*)d_in[0];
    const float* Wq = (const float*)d_in[1];
    const float* Wk = (const float*)d_in[2];
    const float* Wv = (const float*)d_in[3];
    const float* Wo = (const float*)d_in[4];
    const float* bo = (const float*)d_in[5];
    float* out = (float*)d_out;

    f16* Xp  = (f16*)d_ws;             // 8,388,608 (packed X) — dead after qkv
    f16* AO  = Xp;                     // alias: packed AO (2,097,152) reuses Xp
    f16* Wp  = Xp  + 8388608;          // 3,145,728 (packed Wq'|Wk|Wv)
    f16* Wrp = Wp  + 3145728;          // 1,048,576 (packed folded Wo)
    f16* Qws = Wrp + 1048576;          // 2,097,152 (B,4,S,D)
    f16* Kws = Qws + 2097152;          // 2,097,152 (attn-packed tiles)
    f16* Vws = Kws + 2097152;          // 2,097,152 (attn-packed tiles)
    // total 18,874,368 f16 = 36 MiB

    cvt_pack<<<dim3(6144), 256, 0, stream>>>(x, Wq, Wk, Wv, Wo, Xp, Wp, Wrp);
    qkv_gemm<<<dim3(768), 256, 0, stream>>>(Xp, Wp, Qws, Kws, Vws);
    attn_win<<<dim3(256), 256, 0, stream>>>(Qws, Kws, Vws, AO);
    out_gemm<<<dim3(1024), 256, 0, stream>>>(AO, Wrp, bo, out);
}